// Round 4
// baseline (202.522 us; speedup 1.0000x reference)
//
#include <hip/hip_runtime.h>

constexpr int NC = 32;    // channels C
constexpr int NH = 8;     // heads
constexpr int NS = 128;   // s
constexpr int NI = 256;   // i (q rows)
constexpr int NJ = 256;   // j (kv rows)
constexpr float LN_EPS = 1e-5f;
constexpr float QSCALE = 0.17677669529663687f;   // C^-0.5
constexpr float LOG2E  = 1.4426950408889634f;

typedef __bf16 bf16x8 __attribute__((ext_vector_type(8)));
typedef __bf16 bf16x2 __attribute__((ext_vector_type(2)));
typedef float floatx4 __attribute__((ext_vector_type(4)));

__device__ __forceinline__ float fexp2(float x) {
#if __has_builtin(__builtin_amdgcn_exp2f)
    return __builtin_amdgcn_exp2f(x);
#else
    return exp2f(x);
#endif
}
__device__ __forceinline__ float frcp(float x) {
#if __has_builtin(__builtin_amdgcn_rcpf)
    return __builtin_amdgcn_rcpf(x);
#else
    return 1.0f / x;
#endif
}
// HW bf16 pack (v_cvt_pk_bf16_f32 on gfx950), RNE
__device__ __forceinline__ unsigned pk2c(float a, float b) {
    union { bf16x2 v; unsigned u; } c;
    c.v = bf16x2{(__bf16)a, (__bf16)b};
    return c.u;
}

// XOR-swizzled LDS offsets (shorts). Rows of 32 shorts (4 x 16B chunks):
// phys_chunk = chunk ^ ((row>>1)&3)  -> <=2-way banks on all b128 reads.
__device__ __forceinline__ int qkOff(int row, int chunk) {
    return row * 32 + ((chunk ^ ((row >> 1) & 3)) << 3);
}
// V^T rows of 256 shorts (32 chunks): phys_chunk = chunk ^ (c&7).
__device__ __forceinline__ int vOff(int c, int chunk) {
    return c * 256 + ((chunk ^ (c & 7)) << 3);
}
// Per-wave P slab (16 rows x 32 shorts), same swizzle family as qkOff.
__device__ __forceinline__ int pOff(int wbase, int row, int chunk) {
    return wbase + row * 32 + ((chunk ^ ((row >> 1) & 3)) << 3);
}

// ---------------------------------------------------------------------------
// Kernel 1 (merged): blocks 0..255   : pair bias -> fp32 MFMA-C-fragment layout
//                    blocks 256..271 : wq/wk/wv/wg fragment prep (bf16)
//                    blocks 272..275 : wo B-fragment prep (bf16)
// bias32 layout: off(h,i,j) = h*65536 + jc*8192 + w*2048 + (jt*4+it)*256 + l*4 + r
//   (w/it here are the 4-wave coords: w = i>>6, it = (i>>4)&3; log2e folded in.)
// ---------------------------------------------------------------------------
__global__ __launch_bounds__(256) void biasprep_kernel(
    const float* __restrict__ z, const float* __restrict__ lnb_s,
    const float* __restrict__ lnb_b, const float* __restrict__ wb,
    const float* __restrict__ wq, const float* __restrict__ wk,
    const float* __restrict__ wv, const float* __restrict__ wg,
    const float* __restrict__ wo,
    float* __restrict__ bias32, unsigned short* __restrict__ wprep,
    unsigned short* __restrict__ wofrag)
{
    const int b = blockIdx.x;
    const int t = threadIdx.x;
    if (b < 256) {
        // ---- bias: block = one i, threads = j. Coalesced z stage via LDS. ----
        __shared__ float zL[256 * 33];               // pitch 33: conflict-free rows
        const float4* src = (const float4*)(z + (size_t)b * NJ * NC);
#pragma unroll
        for (int k = 0; k < 8; ++k) {
            int idx = t + 256 * k;                   // float4 index
            float4 v = src[idx];
            int f = idx * 4;
            int j = f >> 5, c = f & 31;
            zL[j * 33 + c]     = v.x; zL[j * 33 + c + 1] = v.y;
            zL[j * 33 + c + 2] = v.z; zL[j * 33 + c + 3] = v.w;
        }
        __syncthreads();

        float x[NC];
#pragma unroll
        for (int c = 0; c < NC; ++c) x[c] = zL[t * 33 + c];
        float mu = 0.f;
#pragma unroll
        for (int c = 0; c < NC; ++c) mu += x[c];
        mu *= (1.0f / NC);
        float var = 0.f;
#pragma unroll
        for (int c = 0; c < NC; ++c) { float d = x[c] - mu; var += d * d; }
        var *= (1.0f / NC);
        float rs = rsqrtf(var + LN_EPS);
        float acc[NH];
#pragma unroll
        for (int h = 0; h < NH; ++h) acc[h] = 0.f;
#pragma unroll
        for (int c = 0; c < NC; ++c) {
            float xn = (x[c] - mu) * rs * lnb_s[c] + lnb_b[c];
#pragma unroll
            for (int h = 0; h < NH; ++h) acc[h] += xn * wb[c * NH + h];
        }
        const int i = b;
        const int w_ = i >> 6, it = (i >> 4) & 3, lm = i & 15;
        const int jc = t >> 5, jt = (t >> 4) & 1, lq = (t >> 2) & 3, r = t & 3;
        const int base = jc * 8192 + w_ * 2048 + (jt * 4 + it) * 256
                       + (lq * 16 + lm) * 4 + r;
#pragma unroll
        for (int h = 0; h < NH; ++h)
            bias32[h * 65536 + base] = acc[h] * LOG2E;
    } else if (b < 272) {
        // ---- QKVG weight fragments ----
        int g = (b - 256) * 256 + t;                 // 0..4095
        int p  = g >> 10;
        int h  = (g >> 7) & 7;
        int ct = (g >> 6) & 1;
        int l  = g & 63;
        const float* W = (p == 0) ? wq : (p == 1) ? wk : (p == 2) ? wv : wg;
        float scale = (p == 0) ? QSCALE * LOG2E : (p == 3) ? LOG2E : 1.0f;
        int col = 32 * h + 16 * ct + (l & 15);
        int r0  = 8 * (l >> 4);
        float v[8];
#pragma unroll
        for (int e = 0; e < 8; ++e) v[e] = W[(r0 + e) * 256 + col] * scale;
        uint4 u;
        u.x = pk2c(v[0], v[1]); u.y = pk2c(v[2], v[3]);
        u.z = pk2c(v[4], v[5]); u.w = pk2c(v[6], v[7]);
        *(uint4*)&wprep[g * 8] = u;
    } else {
        // ---- wo B-fragments ----
        int g = (b - 272) * 256 + t;                 // 0..1023
        int tile = g >> 6;                           // kt*2+nt
        int l = g & 63;
        int kt = tile >> 1, nt = tile & 1;
        int r0 = kt * 32 + 8 * (l >> 4);
        int col = nt * 16 + (l & 15);
        float v[8];
#pragma unroll
        for (int e = 0; e < 8; ++e) v[e] = wo[(r0 + e) * 32 + col];
        uint4 u;
        u.x = pk2c(v[0], v[1]); u.y = pk2c(v[2], v[3]);
        u.z = pk2c(v[4], v[5]); u.w = pk2c(v[6], v[7]);
        *(uint4*)&wofrag[g * 8] = u;
    }
}

// ---------------------------------------------------------------------------
// Kernel 2: all-MFMA fused attention. 512 threads / 8 waves per block, each
// wave owns 32 i rows (2 it tiles). 40 KB LDS -> 4 blocks/CU = 32 waves/CU
// (8/SIMD, 2x the 4-wave version) -- the kernel is dependency-stall-bound
// (R1: MfmaUtil 11%, VALUBusy 21%, nothing saturated), so resident-wave
// count is the lever. __launch_bounds__(512,8) targets <=64 VGPR.
// j-loop = 8 K32 MFMA/jc/wave; denominator on VALU; P transposed through a
// 1 KB/wave slab (wave-private, in-order DS pipe, no barrier in loop).
// LDS: KX (X -> Q^T -> K) 16K | Vt (V^T [c][j]) 16K | Pbuf 8K = 40 KB.
// ---------------------------------------------------------------------------
__global__ __launch_bounds__(512, 8) void attn_kernel(
    const float* __restrict__ m, const float* __restrict__ ln_s,
    const float* __restrict__ ln_b,
    const unsigned short* __restrict__ wprep,
    const float* __restrict__ bias32,
    unsigned short* __restrict__ attn16)
{
    __shared__ unsigned short KX[256 * 32];   // X -> Q^T -> K rows (qkOff swizzle)
    __shared__ unsigned short Vt[32 * 256];   // V^T [c][j] (vOff swizzle)
    __shared__ unsigned short Pbuf[8 * 512];  // per-wave P slab (16 x 32)

    const int t = threadIdx.x;
    const int h = blockIdx.x & 7;
    const int s = blockIdx.x >> 3;
    const int l = t & 63, w = t >> 6;         // w in 0..7
    const int lm = l & 15, lq = l >> 4;
    const int ibase = w * 32;                 // 32 i rows per wave
    const int pwb = w * 512;
    const floatx4 zero = {0.f, 0.f, 0.f, 0.f};

    // ---- Phase 1: LN(m[s][t]) -> KX row t (threads 0..255 only). ----
    if (t < NI) {
        const float4* mr = (const float4*)(m + ((size_t)s * NI + t) * NC);
        float x[NC];
#pragma unroll
        for (int k = 0; k < 8; ++k) {
            float4 v = mr[k];
            x[4*k] = v.x; x[4*k+1] = v.y; x[4*k+2] = v.z; x[4*k+3] = v.w;
        }
        float mu = 0.f;
#pragma unroll
        for (int c = 0; c < NC; ++c) mu += x[c];
        mu *= (1.0f / NC);
        float var = 0.f;
#pragma unroll
        for (int c = 0; c < NC; ++c) { float d = x[c] - mu; var += d * d; }
        var *= (1.0f / NC);
        float rs = rsqrtf(var + LN_EPS);
#pragma unroll
        for (int k = 0; k < 4; ++k) {
            uint4 u;
            u.x = pk2c((x[8*k+0]-mu)*rs*ln_s[8*k+0]+ln_b[8*k+0],
                       (x[8*k+1]-mu)*rs*ln_s[8*k+1]+ln_b[8*k+1]);
            u.y = pk2c((x[8*k+2]-mu)*rs*ln_s[8*k+2]+ln_b[8*k+2],
                       (x[8*k+3]-mu)*rs*ln_s[8*k+3]+ln_b[8*k+3]);
            u.z = pk2c((x[8*k+4]-mu)*rs*ln_s[8*k+4]+ln_b[8*k+4],
                       (x[8*k+5]-mu)*rs*ln_s[8*k+5]+ln_b[8*k+5]);
            u.w = pk2c((x[8*k+6]-mu)*rs*ln_s[8*k+6]+ln_b[8*k+6],
                       (x[8*k+7]-mu)*rs*ln_s[8*k+7]+ln_b[8*k+7]);
            *(uint4*)&KX[qkOff(t, k)] = u;
        }
    }
    __syncthreads();   // X rows now cross-wave (8 waves read 4 waves' writes)

    // ---- Phase 2: MFMA projections. Gate deferred to epilogue. ----
    const unsigned short* wp = wprep + ((size_t)h * 128 + l) * 8;
    bf16x8 wfQ[2], wfK[2], wfV[2];
#pragma unroll
    for (int ct = 0; ct < 2; ++ct) {
        wfQ[ct] = *(const bf16x8*)&wp[(0 * 1024 + ct * 64) * 8];
        wfK[ct] = *(const bf16x8*)&wp[(1 * 1024 + ct * 64) * 8];
        wfV[ct] = *(const bf16x8*)&wp[(2 * 1024 + ct * 64) * 8];
    }
    bf16x8 Xb[2];                                 // retained for epilogue gate
#pragma unroll
    for (int it = 0; it < 2; ++it)
        Xb[it] = *(const bf16x8*)&KX[qkOff(ibase + it * 16 + lm, lq)];
    // own KX rows now dead for this wave -> reuse for Q^T (wave-private rows)

    // Q^T rows [i][c]  (D[c][i]: lane lm = i, regs = 4 consecutive c)
#pragma unroll
    for (int it = 0; it < 2; ++it)
#pragma unroll
        for (int ct = 0; ct < 2; ++ct) {
            floatx4 d = __builtin_amdgcn_mfma_f32_16x16x32_bf16(wfQ[ct], Xb[it], zero, 0, 0, 0);
            uint2 u; u.x = pk2c(d[0], d[1]); u.y = pk2c(d[2], d[3]);
            int row = ibase + it * 16 + lm;
            *(uint2*)&KX[qkOff(row, 2 * ct + (lq >> 1)) + (lq & 1) * 4] = u;
        }
    // Hoist own Q^T B-frags BEFORE K overwrites the same rows
    bf16x8 Qb[2];
#pragma unroll
    for (int it = 0; it < 2; ++it)
        Qb[it] = *(const bf16x8*)&KX[qkOff(ibase + it * 16 + lm, lq)];

    // K rows [j][c] -> KX (overwrite Q^T; own rows, in-order DS pipe)
#pragma unroll
    for (int it = 0; it < 2; ++it)
#pragma unroll
        for (int ct = 0; ct < 2; ++ct) {
            floatx4 d = __builtin_amdgcn_mfma_f32_16x16x32_bf16(wfK[ct], Xb[it], zero, 0, 0, 0);
            uint2 u; u.x = pk2c(d[0], d[1]); u.y = pk2c(d[2], d[3]);
            int row = ibase + it * 16 + lm;
            *(uint2*)&KX[qkOff(row, 2 * ct + (lq >> 1)) + (lq & 1) * 4] = u;
        }

    // V -> Vt [c][j]  (D[j][c']: lane lm = c', regs = 4 consecutive j)
    // wave w covers j in [32w, 32w+32) -> chunks 4w + 2*jt + (lq>>1)
#pragma unroll
    for (int jt = 0; jt < 2; ++jt)
#pragma unroll
        for (int ct = 0; ct < 2; ++ct) {
            floatx4 d = __builtin_amdgcn_mfma_f32_16x16x32_bf16(Xb[jt], wfV[ct], zero, 0, 0, 0);
            uint2 u; u.x = pk2c(d[0], d[1]); u.y = pk2c(d[2], d[3]);
            int c = ct * 16 + lm;
            int chunk = 4 * w + 2 * jt + (lq >> 1);
            *(uint2*)&Vt[vOff(c, chunk) + (lq & 1) * 4] = u;
        }

    __syncthreads();   // KX (K) / Vt visible to all waves

    floatx4 accO[2][2];
#pragma unroll
    for (int ct = 0; ct < 2; ++ct)
#pragma unroll
        for (int it = 0; it < 2; ++it) accO[ct][it] = zero;
    float accLv[2] = {0.f, 0.f};                  // denominator, VALU (lane = i)

    // bias fragment coords: oldw = w>>1, oldit = (w&1)*2 + it
    const float* bptr = bias32 + (size_t)h * 65536 + (w >> 1) * 2048 + l * 4;

    // ---- Phase 3: j-loop, 32 j per iteration; 8 K32 MFMA issues/wave ----
    for (int jc = 0; jc < 8; ++jc) {
        const float* bj = bptr + jc * 8192;
        bf16x8 Ka0 = *(const bf16x8*)&KX[qkOff(jc * 32 + lm, lq)];
        bf16x8 Ka1 = *(const bf16x8*)&KX[qkOff(jc * 32 + 16 + lm, lq)];
        bf16x8 Va0 = *(const bf16x8*)&Vt[vOff(lm, 4 * jc + lq)];
        bf16x8 Va1 = *(const bf16x8*)&Vt[vOff(16 + lm, 4 * jc + lq)];
#pragma unroll
        for (int it = 0; it < 2; ++it) {
            const int oit = (w & 1) * 2 + it;
            floatx4 C0 = *(const floatx4*)(bj + oit * 256);
            floatx4 S0 = __builtin_amdgcn_mfma_f32_16x16x32_bf16(Ka0, Qb[it], C0, 0, 0, 0);
            floatx4 C1 = *(const floatx4*)(bj + (4 + oit) * 256);
            floatx4 S1 = __builtin_amdgcn_mfma_f32_16x16x32_bf16(Ka1, Qb[it], C1, 0, 0, 0);
            float p0 = fexp2(S0[0]), p1 = fexp2(S0[1]);
            float p2 = fexp2(S0[2]), p3 = fexp2(S0[3]);
            float p4 = fexp2(S1[0]), p5 = fexp2(S1[1]);
            float p6 = fexp2(S1[2]), p7 = fexp2(S1[3]);
            accLv[it] += ((p0 + p1) + (p2 + p3)) + ((p4 + p5) + (p6 + p7));
            uint2 u0; u0.x = pk2c(p0, p1); u0.y = pk2c(p2, p3);
            uint2 u1; u1.x = pk2c(p4, p5); u1.y = pk2c(p6, p7);
            // j = 16*jt + 4*lq + r -> chunk = 2*jt + (lq>>1), off (lq&1)*4
            *(uint2*)&Pbuf[pOff(pwb, lm, 0 + (lq >> 1)) + (lq & 1) * 4] = u0;
            *(uint2*)&Pbuf[pOff(pwb, lm, 2 + (lq >> 1)) + (lq & 1) * 4] = u1;
            bf16x8 Pb = *(const bf16x8*)&Pbuf[pOff(pwb, lm, lq)];
            accO[0][it] = __builtin_amdgcn_mfma_f32_16x16x32_bf16(Va0, Pb, accO[0][it], 0, 0, 0);
            accO[1][it] = __builtin_amdgcn_mfma_f32_16x16x32_bf16(Va1, Pb, accO[1][it], 0, 0, 0);
        }
    }

    // ---- Epilogue: reduce L over lq, gate from retained Xb, store ----
    // accO / gate orientation: lane lm = i, regs = c' (4*lq + r per ct).
    {
        bf16x8 wfG0 = *(const bf16x8*)&wp[(3 * 1024 + 0 * 64) * 8];
        bf16x8 wfG1 = *(const bf16x8*)&wp[(3 * 1024 + 1 * 64) * 8];
#pragma unroll
        for (int it = 0; it < 2; ++it) {
            float L = accLv[it];
            L += __shfl_xor(L, 16, 64);
            L += __shfl_xor(L, 32, 64);
            const float inv = frcp(L);               // L[i = ibase + it*16 + lm]
            floatx4 d0 = __builtin_amdgcn_mfma_f32_16x16x32_bf16(wfG0, Xb[it], zero, 0, 0, 0);
            floatx4 d1 = __builtin_amdgcn_mfma_f32_16x16x32_bf16(wfG1, Xb[it], zero, 0, 0, 0);
            const size_t rowb = ((size_t)s * NI + ibase + it * 16 + lm) * 256 + h * 32;
            {
                float o0 = accO[0][it][0] * inv * frcp(1.0f + fexp2(-d0[0]));
                float o1 = accO[0][it][1] * inv * frcp(1.0f + fexp2(-d0[1]));
                float o2 = accO[0][it][2] * inv * frcp(1.0f + fexp2(-d0[2]));
                float o3 = accO[0][it][3] * inv * frcp(1.0f + fexp2(-d0[3]));
                uint2 u; u.x = pk2c(o0, o1); u.y = pk2c(o2, o3);
                *(uint2*)&attn16[rowb + 0 * 16 + lq * 4] = u;
            }
            {
                float o0 = accO[1][it][0] * inv * frcp(1.0f + fexp2(-d1[0]));
                float o1 = accO[1][it][1] * inv * frcp(1.0f + fexp2(-d1[1]));
                float o2 = accO[1][it][2] * inv * frcp(1.0f + fexp2(-d1[2]));
                float o3 = accO[1][it][3] * inv * frcp(1.0f + fexp2(-d1[3]));
                uint2 u; u.x = pk2c(o0, o1); u.y = pk2c(o2, o3);
                *(uint2*)&attn16[rowb + 1 * 16 + lq * 4] = u;
            }
        }
    }
}

// ---------------------------------------------------------------------------
// Kernel 3: MFMA output projection. out = attn16(32768x256) @ wo(256x32) + bo
// ---------------------------------------------------------------------------
__global__ __launch_bounds__(256) void proj_kernel(
    const unsigned short* __restrict__ attn16,
    const unsigned short* __restrict__ wofrag,
    const float* __restrict__ bo, float* __restrict__ out)
{
    const int t = threadIdx.x;
    const int l = t & 63, w = t >> 6;
    const int lm = l & 15, lq = l >> 4;
    const int row0 = blockIdx.x * 128 + w * 32;
    const floatx4 zero = {0.f, 0.f, 0.f, 0.f};

    floatx4 acc[2][2];
#pragma unroll
    for (int it = 0; it < 2; ++it)
#pragma unroll
        for (int nt = 0; nt < 2; ++nt) acc[it][nt] = zero;

#pragma unroll 2
    for (int kt = 0; kt < 8; ++kt) {
        bf16x8 a0 = *(const bf16x8*)&attn16[(size_t)(row0 + lm) * 256 + kt * 32 + lq * 8];
        bf16x8 a1 = *(const bf16x8*)&attn16[(size_t)(row0 + 16 + lm) * 256 + kt * 32 + lq * 8];
        bf16x8 b0 = *(const bf16x8*)&wofrag[((kt * 2 + 0) * 64 + l) * 8];
        bf16x8 b1 = *(const bf16x8*)&wofrag[((kt * 2 + 1) * 64 + l) * 8];
        acc[0][0] = __builtin_amdgcn_mfma_f32_16x16x32_bf16(a0, b0, acc[0][0], 0, 0, 0);
        acc[0][1] = __builtin_amdgcn_mfma_f32_16x16x32_bf16(a0, b1, acc[0][1], 0, 0, 0);
        acc[1][0] = __builtin_amdgcn_mfma_f32_16x16x32_bf16(a1, b0, acc[1][0], 0, 0, 0);
        acc[1][1] = __builtin_amdgcn_mfma_f32_16x16x32_bf16(a1, b1, acc[1][1], 0, 0, 0);
    }

    float bov[2] = {bo[lm], bo[16 + lm]};
#pragma unroll
    for (int it = 0; it < 2; ++it)
#pragma unroll
        for (int nt = 0; nt < 2; ++nt)
#pragma unroll
            for (int r = 0; r < 4; ++r)
                out[(size_t)(row0 + it * 16 + lq * 4 + r) * NC + nt * 16 + lm]
                    = acc[it][nt][r] + bov[nt];
}

// ---------------------------------------------------------------------------
extern "C" void kernel_launch(void* const* d_in, const int* in_sizes, int n_in,
                              void* d_out, int out_size, void* d_ws, size_t ws_size,
                              hipStream_t stream) {
    const float* m     = (const float*)d_in[0];
    const float* z     = (const float*)d_in[1];
    const float* ln_s  = (const float*)d_in[2];
    const float* ln_b  = (const float*)d_in[3];
    const float* lnb_s = (const float*)d_in[4];
    const float* lnb_b = (const float*)d_in[5];
    const float* wq    = (const float*)d_in[6];
    const float* wk    = (const float*)d_in[7];
    const float* wv    = (const float*)d_in[8];
    const float* wb    = (const float*)d_in[9];
    const float* wg    = (const float*)d_in[10];
    const float* wo    = (const float*)d_in[11];
    const float* bo    = (const float*)d_in[12];
    float* out = (float*)d_out;

    // ws: bias32 2 MB | wprep 64 KB | wofrag 16 KB | attn16 16.78 MB
    float* bias32 = (float*)d_ws;
    unsigned short* wprep  = (unsigned short*)((char*)d_ws + (2u << 20));
    unsigned short* wofrag = (unsigned short*)((char*)d_ws + (2u << 20) + 65536);
    unsigned short* attn16 = (unsigned short*)((char*)d_ws + (2u << 20) + 65536 + 16384);

    biasprep_kernel<<<276, 256, 0, stream>>>(z, lnb_s, lnb_b, wb, wq, wk, wv, wg,
                                             wo, bias32, wprep, wofrag);
    attn_kernel<<<NS * NH, 512, 0, stream>>>(m, ln_s, ln_b, wprep, bias32, attn16);
    proj_kernel<<<(NS * NI) / 128, 256, 0, stream>>>(attn16, wofrag, bo, out);
}

// Round 5
// 150.075 us; speedup vs baseline: 1.3495x; 1.3495x over previous
//
#include <hip/hip_runtime.h>

constexpr int NC = 32;    // channels C
constexpr int NH = 8;     // heads
constexpr int NS = 128;   // s
constexpr int NI = 256;   // i (q rows)
constexpr int NJ = 256;   // j (kv rows)
constexpr float LN_EPS = 1e-5f;
constexpr float QSCALE = 0.17677669529663687f;   // C^-0.5
constexpr float LOG2E  = 1.4426950408889634f;

typedef __bf16 bf16x8 __attribute__((ext_vector_type(8)));
typedef __bf16 bf16x2 __attribute__((ext_vector_type(2)));
typedef float floatx4 __attribute__((ext_vector_type(4)));

__device__ __forceinline__ float fexp2(float x) {
#if __has_builtin(__builtin_amdgcn_exp2f)
    return __builtin_amdgcn_exp2f(x);
#else
    return exp2f(x);
#endif
}
__device__ __forceinline__ float frcp(float x) {
#if __has_builtin(__builtin_amdgcn_rcpf)
    return __builtin_amdgcn_rcpf(x);
#else
    return 1.0f / x;
#endif
}
// HW bf16 pack (v_cvt_pk_bf16_f32 on gfx950), RNE
__device__ __forceinline__ unsigned pk2c(float a, float b) {
    union { bf16x2 v; unsigned u; } c;
    c.v = bf16x2{(__bf16)a, (__bf16)b};
    return c.u;
}

// XOR-swizzled LDS offsets (shorts). Rows of 32 shorts (4 x 16B chunks):
// phys_chunk = chunk ^ ((row>>1)&3)  -> <=2-way banks on all b128 reads.
__device__ __forceinline__ int qkOff(int row, int chunk) {
    return row * 32 + ((chunk ^ ((row >> 1) & 3)) << 3);
}
// V^T rows of 256 shorts (32 chunks): phys_chunk = chunk ^ (c&7).
__device__ __forceinline__ int vOff(int c, int chunk) {
    return c * 256 + ((chunk ^ (c & 7)) << 3);
}
// Per-wave 16x32 slab, same swizzle family as qkOff.
__device__ __forceinline__ int pOff(int wbase, int row, int chunk) {
    return wbase + row * 32 + ((chunk ^ ((row >> 1) & 3)) << 3);
}

// ---------------------------------------------------------------------------
// Kernel 1 (merged): blocks 0..255   : pair bias -> fp32 MFMA-C-fragment layout
//                    blocks 256..271 : wq/wk/wv/wg fragment prep (bf16)
//                    blocks 272..275 : wo B-fragment prep (bf16)
// bias32 layout: off(h,i,j) = h*65536 + jc*8192 + w_*2048 + (jt*4+it)*256
//                + (lq*16+lm)*4 + r   where i = w_*64+it*16+lm,
//                j = jc*32+jt*16+lq*4+r; log2e folded in (exp2 path).
// ---------------------------------------------------------------------------
__global__ __launch_bounds__(256) void biasprep_kernel(
    const float* __restrict__ z, const float* __restrict__ lnb_s,
    const float* __restrict__ lnb_b, const float* __restrict__ wb,
    const float* __restrict__ wq, const float* __restrict__ wk,
    const float* __restrict__ wv, const float* __restrict__ wg,
    const float* __restrict__ wo,
    float* __restrict__ bias32, unsigned short* __restrict__ wprep,
    unsigned short* __restrict__ wofrag)
{
    const int b = blockIdx.x;
    const int t = threadIdx.x;
    if (b < 256) {
        // ---- bias: block = one i, threads = j. Coalesced z stage via LDS. ----
        __shared__ float zL[256 * 33];               // pitch 33: conflict-free rows
        const float4* src = (const float4*)(z + (size_t)b * NJ * NC);
#pragma unroll
        for (int k = 0; k < 8; ++k) {
            int idx = t + 256 * k;                   // float4 index
            float4 v = src[idx];
            int f = idx * 4;
            int j = f >> 5, c = f & 31;
            zL[j * 33 + c]     = v.x; zL[j * 33 + c + 1] = v.y;
            zL[j * 33 + c + 2] = v.z; zL[j * 33 + c + 3] = v.w;
        }
        __syncthreads();

        float x[NC];
#pragma unroll
        for (int c = 0; c < NC; ++c) x[c] = zL[t * 33 + c];
        float mu = 0.f;
#pragma unroll
        for (int c = 0; c < NC; ++c) mu += x[c];
        mu *= (1.0f / NC);
        float var = 0.f;
#pragma unroll
        for (int c = 0; c < NC; ++c) { float d = x[c] - mu; var += d * d; }
        var *= (1.0f / NC);
        float rs = rsqrtf(var + LN_EPS);
        float acc[NH];
#pragma unroll
        for (int h = 0; h < NH; ++h) acc[h] = 0.f;
#pragma unroll
        for (int c = 0; c < NC; ++c) {
            float xn = (x[c] - mu) * rs * lnb_s[c] + lnb_b[c];
#pragma unroll
            for (int h = 0; h < NH; ++h) acc[h] += xn * wb[c * NH + h];
        }
        const int i = b;
        const int w_ = i >> 6, it = (i >> 4) & 3, lm = i & 15;
        const int jc = t >> 5, jt = (t >> 4) & 1, lq = (t >> 2) & 3, r = t & 3;
        const int base = jc * 8192 + w_ * 2048 + (jt * 4 + it) * 256
                       + (lq * 16 + lm) * 4 + r;
#pragma unroll
        for (int h = 0; h < NH; ++h)
            bias32[h * 65536 + base] = acc[h] * LOG2E;
    } else if (b < 272) {
        // ---- QKVG weight fragments ----
        int g = (b - 256) * 256 + t;                 // 0..4095
        int p  = g >> 10;
        int h  = (g >> 7) & 7;
        int ct = (g >> 6) & 1;
        int l  = g & 63;
        const float* W = (p == 0) ? wq : (p == 1) ? wk : (p == 2) ? wv : wg;
        float scale = (p == 0) ? QSCALE * LOG2E : (p == 3) ? LOG2E : 1.0f;
        int col = 32 * h + 16 * ct + (l & 15);
        int r0  = 8 * (l >> 4);
        float v[8];
#pragma unroll
        for (int e = 0; e < 8; ++e) v[e] = W[(r0 + e) * 256 + col] * scale;
        uint4 u;
        u.x = pk2c(v[0], v[1]); u.y = pk2c(v[2], v[3]);
        u.z = pk2c(v[4], v[5]); u.w = pk2c(v[6], v[7]);
        *(uint4*)&wprep[g * 8] = u;
    } else {
        // ---- wo B-fragments ----
        int g = (b - 272) * 256 + t;                 // 0..1023
        int tile = g >> 6;                           // kt*2+nt
        int l = g & 63;
        int kt = tile >> 1, nt = tile & 1;
        int r0 = kt * 32 + 8 * (l >> 4);
        int col = nt * 16 + (l & 15);
        float v[8];
#pragma unroll
        for (int e = 0; e < 8; ++e) v[e] = wo[(r0 + e) * 32 + col];
        uint4 u;
        u.x = pk2c(v[0], v[1]); u.y = pk2c(v[2], v[3]);
        u.z = pk2c(v[4], v[5]); u.w = pk2c(v[6], v[7]);
        *(uint4*)&wofrag[g * 8] = u;
    }
}

// ---------------------------------------------------------------------------
// Kernel 2 (mega): block = (s, i-quarter), ALL 8 heads inside. 256 thr/4 waves.
// Eliminates proj kernel + 33.5 MB attn16 round-trip + 7/8 LN redundancy:
// per head: K/V (all 256 j) -> LDS, Q^T via wave slab, j-loop, gate+norm,
// o -> slab -> A-frag, projection accumulated in registers across heads
// (accP = mfma(o, wo_frag[h], accP); K-chunk = h), final direct out store.
// LDS: KX (X -> per-head K) 16K | Vt 16K | slab 4K = 36 KB.
// Grid 512 = exactly 2 blocks/CU; __launch_bounds__(256,2) caps VGPR at 128
// (R4 lesson: never force allocation below the live set -> spills).
// ---------------------------------------------------------------------------
__global__ __launch_bounds__(256, 2) void mega_kernel(
    const float* __restrict__ m, const float* __restrict__ ln_s,
    const float* __restrict__ ln_b,
    const unsigned short* __restrict__ wprep,
    const float* __restrict__ bias32,
    const unsigned short* __restrict__ wofrag,
    const float* __restrict__ bo, float* __restrict__ out)
{
    __shared__ unsigned short KX[256 * 32];   // X rows -> per-head K rows
    __shared__ unsigned short Vt[32 * 256];   // per-head V^T [c][j]
    __shared__ unsigned short Pbuf[4 * 512];  // per-wave 16x32 slab (Q^T/P/o)

    const int t = threadIdx.x;
    const int s  = blockIdx.x >> 2;
    const int iq = blockIdx.x & 3;            // i-quarter (64 rows)
    const int l = t & 63, w = t >> 6;
    const int lm = l & 15, lq = l >> 4;
    const int pwb = w * 512;
    const floatx4 zero = {0.f, 0.f, 0.f, 0.f};

    // ---- Phase 1: LN(m[s][t]) -> KX row t (bf16, swizzled). ----
    {
        const float4* mr = (const float4*)(m + ((size_t)s * NI + t) * NC);
        float x[NC];
#pragma unroll
        for (int k = 0; k < 8; ++k) {
            float4 v = mr[k];
            x[4*k] = v.x; x[4*k+1] = v.y; x[4*k+2] = v.z; x[4*k+3] = v.w;
        }
        float mu = 0.f;
#pragma unroll
        for (int c = 0; c < NC; ++c) mu += x[c];
        mu *= (1.0f / NC);
        float var = 0.f;
#pragma unroll
        for (int c = 0; c < NC; ++c) { float d = x[c] - mu; var += d * d; }
        var *= (1.0f / NC);
        float rs = rsqrtf(var + LN_EPS);
#pragma unroll
        for (int k = 0; k < 4; ++k) {
            uint4 u;
            u.x = pk2c((x[8*k+0]-mu)*rs*ln_s[8*k+0]+ln_b[8*k+0],
                       (x[8*k+1]-mu)*rs*ln_s[8*k+1]+ln_b[8*k+1]);
            u.y = pk2c((x[8*k+2]-mu)*rs*ln_s[8*k+2]+ln_b[8*k+2],
                       (x[8*k+3]-mu)*rs*ln_s[8*k+3]+ln_b[8*k+3]);
            u.z = pk2c((x[8*k+4]-mu)*rs*ln_s[8*k+4]+ln_b[8*k+4],
                       (x[8*k+5]-mu)*rs*ln_s[8*k+5]+ln_b[8*k+5]);
            u.w = pk2c((x[8*k+6]-mu)*rs*ln_s[8*k+6]+ln_b[8*k+6],
                       (x[8*k+7]-mu)*rs*ln_s[8*k+7]+ln_b[8*k+7]);
            *(uint4*)&KX[qkOff(t, k)] = u;
        }
    }
    __syncthreads();   // X rows visible to all waves

    // ---- Hoist X fragments to registers (held for all 8 heads) ----
    bf16x8 Xb4[4];                 // rows w*64 + it*16 + lm : K/V projection span
#pragma unroll
    for (int it = 0; it < 4; ++it)
        Xb4[it] = *(const bf16x8*)&KX[qkOff(w * 64 + it * 16 + lm, lq)];
    bf16x8 Xq = *(const bf16x8*)&KX[qkOff(iq * 64 + w * 16 + lm, lq)];  // own Q/gate rows

    floatx4 accP[2] = {zero, zero};          // projection accumulator (over heads)

    for (int h = 0; h < NH; ++h) {
        const unsigned short* wp = wprep + ((size_t)h * 128 + l) * 8;
        bf16x8 wfQ[2], wfK[2], wfV[2];
#pragma unroll
        for (int ct = 0; ct < 2; ++ct) {
            wfQ[ct] = *(const bf16x8*)&wp[(0 * 1024 + ct * 64) * 8];
            wfK[ct] = *(const bf16x8*)&wp[(1 * 1024 + ct * 64) * 8];
            wfV[ct] = *(const bf16x8*)&wp[(2 * 1024 + ct * 64) * 8];
        }
        __syncthreads();   // all waves done reading KX/Vt (X or previous head)

        // K rows [j][c] -> KX  (D[m=j][n=c... lane lm = j, regs = 4 c)
#pragma unroll
        for (int it = 0; it < 4; ++it)
#pragma unroll
            for (int ct = 0; ct < 2; ++ct) {
                floatx4 d = __builtin_amdgcn_mfma_f32_16x16x32_bf16(wfK[ct], Xb4[it], zero, 0, 0, 0);
                uint2 u; u.x = pk2c(d[0], d[1]); u.y = pk2c(d[2], d[3]);
                int row = w * 64 + it * 16 + lm;
                *(uint2*)&KX[qkOff(row, 2 * ct + (lq >> 1)) + (lq & 1) * 4] = u;
            }
        // V -> Vt [c][j]  (lane lm = c', regs = 4 consecutive j)
#pragma unroll
        for (int jt = 0; jt < 4; ++jt)
#pragma unroll
            for (int ct = 0; ct < 2; ++ct) {
                floatx4 d = __builtin_amdgcn_mfma_f32_16x16x32_bf16(Xb4[jt], wfV[ct], zero, 0, 0, 0);
                uint2 u; u.x = pk2c(d[0], d[1]); u.y = pk2c(d[2], d[3]);
                int c = ct * 16 + lm;
                int chunk = 8 * w + 2 * jt + (lq >> 1);
                *(uint2*)&Vt[vOff(c, chunk) + (lq & 1) * 4] = u;
            }
        // Q^T via wave-private slab: D lane lm = i, regs = 4 c -> slab -> A..B-frag
#pragma unroll
        for (int ct = 0; ct < 2; ++ct) {
            floatx4 d = __builtin_amdgcn_mfma_f32_16x16x32_bf16(wfQ[ct], Xq, zero, 0, 0, 0);
            uint2 u; u.x = pk2c(d[0], d[1]); u.y = pk2c(d[2], d[3]);
            *(uint2*)&Pbuf[pOff(pwb, lm, 2 * ct + (lq >> 1)) + (lq & 1) * 4] = u;
        }
        bf16x8 Qb = *(const bf16x8*)&Pbuf[pOff(pwb, lm, lq)];

        __syncthreads();   // KX(K)/Vt for head h visible

        float accLv = 0.f;
        floatx4 accO0 = zero, accO1 = zero;
        // bias coords: i = iq*64 + w*16 + lm  ->  w_ = iq, it = w
        const float* bj0 = bias32 + (size_t)h * 65536 + iq * 2048 + w * 256 + l * 4;

        // ---- j-loop: 8 x 32 j; P entirely through the wave slab ----
        for (int jc = 0; jc < 8; ++jc) {
            const float* bj = bj0 + jc * 8192;
            bf16x8 Ka0 = *(const bf16x8*)&KX[qkOff(jc * 32 + lm, lq)];
            bf16x8 Ka1 = *(const bf16x8*)&KX[qkOff(jc * 32 + 16 + lm, lq)];
            bf16x8 Va0 = *(const bf16x8*)&Vt[vOff(lm, 4 * jc + lq)];
            bf16x8 Va1 = *(const bf16x8*)&Vt[vOff(16 + lm, 4 * jc + lq)];
            floatx4 C0 = *(const floatx4*)(bj);            // jt=0: (0*4+w)*256
            floatx4 S0 = __builtin_amdgcn_mfma_f32_16x16x32_bf16(Ka0, Qb, C0, 0, 0, 0);
            floatx4 C1 = *(const floatx4*)(bj + 1024);     // jt=1: (1*4+w)*256
            floatx4 S1 = __builtin_amdgcn_mfma_f32_16x16x32_bf16(Ka1, Qb, C1, 0, 0, 0);
            float p0 = fexp2(S0[0]), p1 = fexp2(S0[1]);
            float p2 = fexp2(S0[2]), p3 = fexp2(S0[3]);
            float p4 = fexp2(S1[0]), p5 = fexp2(S1[1]);
            float p6 = fexp2(S1[2]), p7 = fexp2(S1[3]);
            accLv += ((p0 + p1) + (p2 + p3)) + ((p4 + p5) + (p6 + p7));
            uint2 u0; u0.x = pk2c(p0, p1); u0.y = pk2c(p2, p3);
            uint2 u1; u1.x = pk2c(p4, p5); u1.y = pk2c(p6, p7);
            *(uint2*)&Pbuf[pOff(pwb, lm, 0 + (lq >> 1)) + (lq & 1) * 4] = u0;
            *(uint2*)&Pbuf[pOff(pwb, lm, 2 + (lq >> 1)) + (lq & 1) * 4] = u1;
            bf16x8 Pb = *(const bf16x8*)&Pbuf[pOff(pwb, lm, lq)];
            accO0 = __builtin_amdgcn_mfma_f32_16x16x32_bf16(Va0, Pb, accO0, 0, 0, 0);
            accO1 = __builtin_amdgcn_mfma_f32_16x16x32_bf16(Va1, Pb, accO1, 0, 0, 0);
        }

        // ---- per-head epilogue: L-reduce, gate, o -> slab -> proj-accumulate ----
        {
            float L = accLv;
            L += __shfl_xor(L, 16, 64);
            L += __shfl_xor(L, 32, 64);
            const float inv = frcp(L);                   // L[i = iq*64+w*16+lm]
            bf16x8 wfG0 = *(const bf16x8*)&wp[(3 * 1024 + 0 * 64) * 8];
            bf16x8 wfG1 = *(const bf16x8*)&wp[(3 * 1024 + 1 * 64) * 8];
            floatx4 g0 = __builtin_amdgcn_mfma_f32_16x16x32_bf16(wfG0, Xq, zero, 0, 0, 0);
            floatx4 g1 = __builtin_amdgcn_mfma_f32_16x16x32_bf16(wfG1, Xq, zero, 0, 0, 0);
            float o0 = accO0[0] * inv * frcp(1.0f + fexp2(-g0[0]));
            float o1 = accO0[1] * inv * frcp(1.0f + fexp2(-g0[1]));
            float o2 = accO0[2] * inv * frcp(1.0f + fexp2(-g0[2]));
            float o3 = accO0[3] * inv * frcp(1.0f + fexp2(-g0[3]));
            float o4 = accO1[0] * inv * frcp(1.0f + fexp2(-g1[0]));
            float o5 = accO1[1] * inv * frcp(1.0f + fexp2(-g1[1]));
            float o6 = accO1[2] * inv * frcp(1.0f + fexp2(-g1[2]));
            float o7 = accO1[3] * inv * frcp(1.0f + fexp2(-g1[3]));
            uint2 u0; u0.x = pk2c(o0, o1); u0.y = pk2c(o2, o3);
            uint2 u1; u1.x = pk2c(o4, o5); u1.y = pk2c(o6, o7);
            *(uint2*)&Pbuf[pOff(pwb, lm, 0 + (lq >> 1)) + (lq & 1) * 4] = u0;
            *(uint2*)&Pbuf[pOff(pwb, lm, 2 + (lq >> 1)) + (lq & 1) * 4] = u1;
            bf16x8 of = *(const bf16x8*)&Pbuf[pOff(pwb, lm, lq)];
            bf16x8 wob0 = *(const bf16x8*)&wofrag[((size_t)(h * 2 + 0) * 64 + l) * 8];
            bf16x8 wob1 = *(const bf16x8*)&wofrag[((size_t)(h * 2 + 1) * 64 + l) * 8];
            accP[0] = __builtin_amdgcn_mfma_f32_16x16x32_bf16(of, wob0, accP[0], 0, 0, 0);
            accP[1] = __builtin_amdgcn_mfma_f32_16x16x32_bf16(of, wob1, accP[1], 0, 0, 0);
        }
    }

    // ---- Final store: out rows iq*64 + w*16 + lq*4 + r, cols nt*16 + lm ----
    {
        float bov0 = bo[lm], bov1 = bo[16 + lm];
        const size_t row0 = (size_t)s * NI + iq * 64 + w * 16 + lq * 4;
#pragma unroll
        for (int r = 0; r < 4; ++r) {
            out[(row0 + r) * NC + lm]      = accP[0][r] + bov0;
            out[(row0 + r) * NC + 16 + lm] = accP[1][r] + bov1;
        }
    }
}

// ---------------------------------------------------------------------------
extern "C" void kernel_launch(void* const* d_in, const int* in_sizes, int n_in,
                              void* d_out, int out_size, void* d_ws, size_t ws_size,
                              hipStream_t stream) {
    const float* m     = (const float*)d_in[0];
    const float* z     = (const float*)d_in[1];
    const float* ln_s  = (const float*)d_in[2];
    const float* ln_b  = (const float*)d_in[3];
    const float* lnb_s = (const float*)d_in[4];
    const float* lnb_b = (const float*)d_in[5];
    const float* wq    = (const float*)d_in[6];
    const float* wk    = (const float*)d_in[7];
    const float* wv    = (const float*)d_in[8];
    const float* wb    = (const float*)d_in[9];
    const float* wg    = (const float*)d_in[10];
    const float* wo    = (const float*)d_in[11];
    const float* bo    = (const float*)d_in[12];
    float* out = (float*)d_out;

    // ws: bias32 2 MB | wprep 64 KB | wofrag 16 KB
    float* bias32 = (float*)d_ws;
    unsigned short* wprep  = (unsigned short*)((char*)d_ws + (2u << 20));
    unsigned short* wofrag = (unsigned short*)((char*)d_ws + (2u << 20) + 65536);

    biasprep_kernel<<<276, 256, 0, stream>>>(z, lnb_s, lnb_b, wb, wq, wk, wv, wg,
                                             wo, bias32, wprep, wofrag);
    mega_kernel<<<NS * 4, 256, 0, stream>>>(m, ln_s, ln_b, wprep, bias32,
                                            wofrag, bo, out);
}

// Round 6
// 140.131 us; speedup vs baseline: 1.4452x; 1.0710x over previous
//
#include <hip/hip_runtime.h>

constexpr int NC = 32;    // channels C
constexpr int NH = 8;     // heads
constexpr int NS = 128;   // s
constexpr int NI = 256;   // i (q rows)
constexpr int NJ = 256;   // j (kv rows)
constexpr float LN_EPS = 1e-5f;
constexpr float QSCALE = 0.17677669529663687f;   // C^-0.5
constexpr float LOG2E  = 1.4426950408889634f;

typedef __bf16 bf16x8 __attribute__((ext_vector_type(8)));
typedef __bf16 bf16x2 __attribute__((ext_vector_type(2)));
typedef float floatx4 __attribute__((ext_vector_type(4)));

__device__ __forceinline__ float fexp2(float x) {
#if __has_builtin(__builtin_amdgcn_exp2f)
    return __builtin_amdgcn_exp2f(x);
#else
    return exp2f(x);
#endif
}
__device__ __forceinline__ float frcp(float x) {
#if __has_builtin(__builtin_amdgcn_rcpf)
    return __builtin_amdgcn_rcpf(x);
#else
    return 1.0f / x;
#endif
}
// HW bf16 pack (v_cvt_pk_bf16_f32 on gfx950), RNE
__device__ __forceinline__ unsigned pk2c(float a, float b) {
    union { bf16x2 v; unsigned u; } c;
    c.v = bf16x2{(__bf16)a, (__bf16)b};
    return c.u;
}

// XOR-swizzled LDS offsets (shorts). Rows of 32 shorts (4 x 16B chunks):
// phys_chunk = chunk ^ ((row>>1)&3)  -> <=2-way banks on all b128 reads.
__device__ __forceinline__ int qkOff(int row, int chunk) {
    return row * 32 + ((chunk ^ ((row >> 1) & 3)) << 3);
}
// V^T rows of 256 shorts (32 chunks): phys_chunk = chunk ^ (c&7).
__device__ __forceinline__ int vOff(int c, int chunk) {
    return c * 256 + ((chunk ^ (c & 7)) << 3);
}
// 16x32 slab (per wave, per it), same swizzle family as qkOff.
__device__ __forceinline__ int pOff(int base, int row, int chunk) {
    return base + row * 32 + ((chunk ^ ((row >> 1) & 3)) << 3);
}

// ---------------------------------------------------------------------------
// Kernel 1 (merged): blocks 0..1023  : pair bias, block = (i, j-quarter)
//                    blocks 1024..1039: wq/wk/wv/wg fragment prep (bf16)
//                    blocks 1040..1043: wo B-fragment prep (bf16)
// Regridded 276->1044 blocks: the old 276-block shape was ~1 block/CU =
// 1 wave/SIMD (zero latency hiding). bias32 layout unchanged:
// off(h,i,j) = h*65536 + (j>>5)*8192 + (i>>6)*2048 + (((j>>4)&1)*4+((i>>4)&3))*256
//              + (((j>>2)&3)*16 + (i&15))*4 + (j&3);  log2e folded in.
// ---------------------------------------------------------------------------
__global__ __launch_bounds__(256) void biasprep_kernel(
    const float* __restrict__ z, const float* __restrict__ lnb_s,
    const float* __restrict__ lnb_b, const float* __restrict__ wb,
    const float* __restrict__ wq, const float* __restrict__ wk,
    const float* __restrict__ wv, const float* __restrict__ wg,
    const float* __restrict__ wo,
    float* __restrict__ bias32, unsigned short* __restrict__ wprep,
    unsigned short* __restrict__ wofrag)
{
    const int b = blockIdx.x;
    const int t = threadIdx.x;
    if (b < 1024) {
        // ---- bias: block = (i, jq); 64 j rows staged, 4 thread-groups
        //      each compute all 64 LN rows redundantly but 2 heads each. ----
        __shared__ float zL[64 * 33];                // pitch 33: conflict-free
        const int i  = b >> 2;
        const int jq = b & 3;
        const float4* src = (const float4*)(z + ((size_t)i * NJ + jq * 64) * NC);
#pragma unroll
        for (int k = 0; k < 2; ++k) {
            int idx = t + 256 * k;                   // float4 index 0..511
            float4 v = src[idx];
            int f = idx * 4;
            int jr = f >> 5, c = f & 31;
            zL[jr * 33 + c]     = v.x; zL[jr * 33 + c + 1] = v.y;
            zL[jr * 33 + c + 2] = v.z; zL[jr * 33 + c + 3] = v.w;
        }
        __syncthreads();

        const int jr = t & 63;
        const int h0 = t >> 6;                       // 0..3 -> heads h0, h0+4
        float x[NC];
#pragma unroll
        for (int c = 0; c < NC; ++c) x[c] = zL[jr * 33 + c];
        float mu = 0.f;
#pragma unroll
        for (int c = 0; c < NC; ++c) mu += x[c];
        mu *= (1.0f / NC);
        float var = 0.f;
#pragma unroll
        for (int c = 0; c < NC; ++c) { float d = x[c] - mu; var += d * d; }
        var *= (1.0f / NC);
        float rs = rsqrtf(var + LN_EPS);
        float a0 = 0.f, a1 = 0.f;
#pragma unroll
        for (int c = 0; c < NC; ++c) {
            float xn = (x[c] - mu) * rs * lnb_s[c] + lnb_b[c];
            a0 += xn * wb[c * NH + h0];
            a1 += xn * wb[c * NH + h0 + 4];
        }
        const int j  = jq * 64 + jr;
        const int w_ = i >> 6, it_ = (i >> 4) & 3, lm_ = i & 15;
        const int jcb = j >> 5, jt = (j >> 4) & 1, lqb = (j >> 2) & 3, rb = j & 3;
        const int base = jcb * 8192 + w_ * 2048 + (jt * 4 + it_) * 256
                       + (lqb * 16 + lm_) * 4 + rb;
        bias32[h0 * 65536 + base]       = a0 * LOG2E;
        bias32[(h0 + 4) * 65536 + base] = a1 * LOG2E;
    } else if (b < 1040) {
        // ---- QKVG weight fragments ----
        int g = (b - 1024) * 256 + t;                // 0..4095
        int p  = g >> 10;
        int h  = (g >> 7) & 7;
        int ct = (g >> 6) & 1;
        int l  = g & 63;
        const float* W = (p == 0) ? wq : (p == 1) ? wk : (p == 2) ? wv : wg;
        float scale = (p == 0) ? QSCALE * LOG2E : (p == 3) ? LOG2E : 1.0f;
        int col = 32 * h + 16 * ct + (l & 15);
        int r0  = 8 * (l >> 4);
        float v[8];
#pragma unroll
        for (int e = 0; e < 8; ++e) v[e] = W[(r0 + e) * 256 + col] * scale;
        uint4 u;
        u.x = pk2c(v[0], v[1]); u.y = pk2c(v[2], v[3]);
        u.z = pk2c(v[4], v[5]); u.w = pk2c(v[6], v[7]);
        *(uint4*)&wprep[g * 8] = u;
    } else {
        // ---- wo B-fragments ----
        int g = (b - 1040) * 256 + t;                // 0..1023
        int tile = g >> 6;                           // kt*2+nt
        int l = g & 63;
        int kt = tile >> 1, nt = tile & 1;
        int r0 = kt * 32 + 8 * (l >> 4);
        int col = nt * 16 + (l & 15);
        float v[8];
#pragma unroll
        for (int e = 0; e < 8; ++e) v[e] = wo[(r0 + e) * 32 + col];
        uint4 u;
        u.x = pk2c(v[0], v[1]); u.y = pk2c(v[2], v[3]);
        u.z = pk2c(v[4], v[5]); u.w = pk2c(v[6], v[7]);
        *(uint4*)&wofrag[g * 8] = u;
    }
}

// ---------------------------------------------------------------------------
// Kernel 2: all-MFMA fused attention. 48 KB LDS -> 3 blocks/CU.
// ILP round (R6): the kernel is dependency-stall-bound WITHIN the wave
// (R1: MfmaUtil 11%, VALUBusy 21%; occupancy changes neutral R3/R4/R5).
// Fixes: (a) per-it private P slabs (4 x 1KB/wave) break the same-address
// DS-pipe serialization between consecutive (jc,it) steps; (b) jc-loop
// unrolled x2 -> 8-step independent-chain window for the scheduler.
// Denominator on VALU (lane = i). __launch_bounds__(256,3) = VGPR cap 168
// (R4 lesson: never force allocation below the live set).
// LDS: KX (X -> Q^T -> K) 16K | Vt (V^T [c][j]) 16K | Pbuf 16K = 48 KB.
// ---------------------------------------------------------------------------
__global__ __launch_bounds__(256, 3) void attn_kernel(
    const float* __restrict__ m, const float* __restrict__ ln_s,
    const float* __restrict__ ln_b,
    const unsigned short* __restrict__ wprep,
    const float* __restrict__ bias32,
    unsigned short* __restrict__ attn16)
{
    __shared__ unsigned short KX[256 * 32];    // X -> Q^T -> K rows (qkOff)
    __shared__ unsigned short Vt[32 * 256];    // V^T [c][j] (vOff)
    __shared__ unsigned short Pbuf[4 * 2048];  // per-wave, per-it 16x32 slabs

    const int t = threadIdx.x;
    const int h = blockIdx.x & 7;
    const int s = blockIdx.x >> 3;
    const int l = t & 63, w = t >> 6;
    const int lm = l & 15, lq = l >> 4;
    const int ibase = w * 64;
    const int pwb = w * 2048;
    const floatx4 zero = {0.f, 0.f, 0.f, 0.f};

    // ---- Phase 1: LN(m[s][t]) -> KX row t (bf16, swizzled). Wave-private. ----
    {
        const float4* mr = (const float4*)(m + ((size_t)s * NI + t) * NC);
        float x[NC];
#pragma unroll
        for (int k = 0; k < 8; ++k) {
            float4 v = mr[k];
            x[4*k] = v.x; x[4*k+1] = v.y; x[4*k+2] = v.z; x[4*k+3] = v.w;
        }
        float mu = 0.f;
#pragma unroll
        for (int c = 0; c < NC; ++c) mu += x[c];
        mu *= (1.0f / NC);
        float var = 0.f;
#pragma unroll
        for (int c = 0; c < NC; ++c) { float d = x[c] - mu; var += d * d; }
        var *= (1.0f / NC);
        float rs = rsqrtf(var + LN_EPS);
#pragma unroll
        for (int k = 0; k < 4; ++k) {
            uint4 u;
            u.x = pk2c((x[8*k+0]-mu)*rs*ln_s[8*k+0]+ln_b[8*k+0],
                       (x[8*k+1]-mu)*rs*ln_s[8*k+1]+ln_b[8*k+1]);
            u.y = pk2c((x[8*k+2]-mu)*rs*ln_s[8*k+2]+ln_b[8*k+2],
                       (x[8*k+3]-mu)*rs*ln_s[8*k+3]+ln_b[8*k+3]);
            u.z = pk2c((x[8*k+4]-mu)*rs*ln_s[8*k+4]+ln_b[8*k+4],
                       (x[8*k+5]-mu)*rs*ln_s[8*k+5]+ln_b[8*k+5]);
            u.w = pk2c((x[8*k+6]-mu)*rs*ln_s[8*k+6]+ln_b[8*k+6],
                       (x[8*k+7]-mu)*rs*ln_s[8*k+7]+ln_b[8*k+7]);
            *(uint4*)&KX[qkOff(t, k)] = u;
        }
    }
    // no barrier: wave-private rows; DS pipe is in-order per wave

    // ---- Phase 2: MFMA projections. Gate deferred to epilogue. ----
    const unsigned short* wp = wprep + ((size_t)h * 128 + l) * 8;
    bf16x8 wfQ[2], wfK[2], wfV[2];
#pragma unroll
    for (int ct = 0; ct < 2; ++ct) {
        wfQ[ct] = *(const bf16x8*)&wp[(0 * 1024 + ct * 64) * 8];
        wfK[ct] = *(const bf16x8*)&wp[(1 * 1024 + ct * 64) * 8];
        wfV[ct] = *(const bf16x8*)&wp[(2 * 1024 + ct * 64) * 8];
    }
    bf16x8 Xb[4];                                 // retained for epilogue gate
#pragma unroll
    for (int it = 0; it < 4; ++it)
        Xb[it] = *(const bf16x8*)&KX[qkOff(ibase + it * 16 + lm, lq)];
    // KX (X) now dead for this wave -> reuse rows for Q^T

    // Q^T rows [i][c]  (D[c][i]: lane lm = i, regs = 4 consecutive c)
#pragma unroll
    for (int it = 0; it < 4; ++it)
#pragma unroll
        for (int ct = 0; ct < 2; ++ct) {
            floatx4 d = __builtin_amdgcn_mfma_f32_16x16x32_bf16(wfQ[ct], Xb[it], zero, 0, 0, 0);
            uint2 u; u.x = pk2c(d[0], d[1]); u.y = pk2c(d[2], d[3]);
            int row = ibase + it * 16 + lm;
            *(uint2*)&KX[qkOff(row, 2 * ct + (lq >> 1)) + (lq & 1) * 4] = u;
        }
    // Hoist own Q^T B-frags BEFORE K overwrites the same rows
    bf16x8 Qb[4];
#pragma unroll
    for (int it = 0; it < 4; ++it)
        Qb[it] = *(const bf16x8*)&KX[qkOff(ibase + it * 16 + lm, lq)];

    // K rows [j][c] -> KX (overwrite Q^T; own rows, in-order DS pipe)
#pragma unroll
    for (int it = 0; it < 4; ++it)
#pragma unroll
        for (int ct = 0; ct < 2; ++ct) {
            floatx4 d = __builtin_amdgcn_mfma_f32_16x16x32_bf16(wfK[ct], Xb[it], zero, 0, 0, 0);
            uint2 u; u.x = pk2c(d[0], d[1]); u.y = pk2c(d[2], d[3]);
            int row = ibase + it * 16 + lm;
            *(uint2*)&KX[qkOff(row, 2 * ct + (lq >> 1)) + (lq & 1) * 4] = u;
        }

    // V -> Vt [c][j]  (D[j][c']: lane lm = c', regs = 4 consecutive j)
#pragma unroll
    for (int jt = 0; jt < 4; ++jt)
#pragma unroll
        for (int ct = 0; ct < 2; ++ct) {
            floatx4 d = __builtin_amdgcn_mfma_f32_16x16x32_bf16(Xb[jt], wfV[ct], zero, 0, 0, 0);
            uint2 u; u.x = pk2c(d[0], d[1]); u.y = pk2c(d[2], d[3]);
            int c = ct * 16 + lm;
            int chunk = 8 * w + 2 * jt + (lq >> 1);
            *(uint2*)&Vt[vOff(c, chunk) + (lq & 1) * 4] = u;
        }

    __syncthreads();   // KX (K) / Vt visible to all waves (the only barrier)

    floatx4 accO[2][4];
#pragma unroll
    for (int ct = 0; ct < 2; ++ct)
#pragma unroll
        for (int it = 0; it < 4; ++it) accO[ct][it] = zero;
    float accLv[4] = {0.f, 0.f, 0.f, 0.f};        // denominator, VALU (lane = i)

    const float* bptr = bias32 + (size_t)h * 65536 + w * 2048 + l * 4;

    // ---- Phase 3: j-loop, 32 j/iter, unroll x2; per-it private slabs ----
#pragma unroll 2
    for (int jc = 0; jc < 8; ++jc) {
        const float* bj = bptr + jc * 8192;
        bf16x8 Ka0 = *(const bf16x8*)&KX[qkOff(jc * 32 + lm, lq)];
        bf16x8 Ka1 = *(const bf16x8*)&KX[qkOff(jc * 32 + 16 + lm, lq)];
        bf16x8 Va0 = *(const bf16x8*)&Vt[vOff(lm, 4 * jc + lq)];
        bf16x8 Va1 = *(const bf16x8*)&Vt[vOff(16 + lm, 4 * jc + lq)];
#pragma unroll
        for (int it = 0; it < 4; ++it) {
            const int pb = pwb + it * 512;         // private slab per (wave,it)
            floatx4 C0 = *(const floatx4*)(bj + it * 256);
            floatx4 S0 = __builtin_amdgcn_mfma_f32_16x16x32_bf16(Ka0, Qb[it], C0, 0, 0, 0);
            floatx4 C1 = *(const floatx4*)(bj + (4 + it) * 256);
            floatx4 S1 = __builtin_amdgcn_mfma_f32_16x16x32_bf16(Ka1, Qb[it], C1, 0, 0, 0);
            float p0 = fexp2(S0[0]), p1 = fexp2(S0[1]);
            float p2 = fexp2(S0[2]), p3 = fexp2(S0[3]);
            float p4 = fexp2(S1[0]), p5 = fexp2(S1[1]);
            float p6 = fexp2(S1[2]), p7 = fexp2(S1[3]);
            accLv[it] += ((p0 + p1) + (p2 + p3)) + ((p4 + p5) + (p6 + p7));
            uint2 u0; u0.x = pk2c(p0, p1); u0.y = pk2c(p2, p3);
            uint2 u1; u1.x = pk2c(p4, p5); u1.y = pk2c(p6, p7);
            // j = 16*jt + 4*lq + r -> chunk = 2*jt + (lq>>1), off (lq&1)*4
            *(uint2*)&Pbuf[pOff(pb, lm, 0 + (lq >> 1)) + (lq & 1) * 4] = u0;
            *(uint2*)&Pbuf[pOff(pb, lm, 2 + (lq >> 1)) + (lq & 1) * 4] = u1;
            bf16x8 Pb = *(const bf16x8*)&Pbuf[pOff(pb, lm, lq)];
            accO[0][it] = __builtin_amdgcn_mfma_f32_16x16x32_bf16(Va0, Pb, accO[0][it], 0, 0, 0);
            accO[1][it] = __builtin_amdgcn_mfma_f32_16x16x32_bf16(Va1, Pb, accO[1][it], 0, 0, 0);
        }
    }

    // ---- Epilogue: reduce L over lq, gate from retained Xb, store ----
    // accO / gate orientation: lane lm = i, regs = c' (4*lq + r per ct).
    {
        bf16x8 wfG0 = *(const bf16x8*)&wp[(3 * 1024 + 0 * 64) * 8];
        bf16x8 wfG1 = *(const bf16x8*)&wp[(3 * 1024 + 1 * 64) * 8];
#pragma unroll
        for (int it = 0; it < 4; ++it) {
            float L = accLv[it];
            L += __shfl_xor(L, 16, 64);
            L += __shfl_xor(L, 32, 64);
            const float inv = frcp(L);               // L[i = ibase + it*16 + lm]
            floatx4 d0 = __builtin_amdgcn_mfma_f32_16x16x32_bf16(wfG0, Xb[it], zero, 0, 0, 0);
            floatx4 d1 = __builtin_amdgcn_mfma_f32_16x16x32_bf16(wfG1, Xb[it], zero, 0, 0, 0);
            const size_t rowb = ((size_t)s * NI + ibase + it * 16 + lm) * 256 + h * 32;
            {
                float o0 = accO[0][it][0] * inv * frcp(1.0f + fexp2(-d0[0]));
                float o1 = accO[0][it][1] * inv * frcp(1.0f + fexp2(-d0[1]));
                float o2 = accO[0][it][2] * inv * frcp(1.0f + fexp2(-d0[2]));
                float o3 = accO[0][it][3] * inv * frcp(1.0f + fexp2(-d0[3]));
                uint2 u; u.x = pk2c(o0, o1); u.y = pk2c(o2, o3);
                *(uint2*)&attn16[rowb + 0 * 16 + lq * 4] = u;
            }
            {
                float o0 = accO[1][it][0] * inv * frcp(1.0f + fexp2(-d1[0]));
                float o1 = accO[1][it][1] * inv * frcp(1.0f + fexp2(-d1[1]));
                float o2 = accO[1][it][2] * inv * frcp(1.0f + fexp2(-d1[2]));
                float o3 = accO[1][it][3] * inv * frcp(1.0f + fexp2(-d1[3]));
                uint2 u; u.x = pk2c(o0, o1); u.y = pk2c(o2, o3);
                *(uint2*)&attn16[rowb + 1 * 16 + lq * 4] = u;
            }
        }
    }
}

// ---------------------------------------------------------------------------
// Kernel 3: MFMA output projection. out = attn16(32768x256) @ wo(256x32) + bo
// Regridded 256->512 blocks (64 rows each) for latency hiding (2 blocks/CU).
// ---------------------------------------------------------------------------
__global__ __launch_bounds__(256) void proj_kernel(
    const unsigned short* __restrict__ attn16,
    const unsigned short* __restrict__ wofrag,
    const float* __restrict__ bo, float* __restrict__ out)
{
    const int t = threadIdx.x;
    const int l = t & 63, w = t >> 6;
    const int lm = l & 15, lq = l >> 4;
    const int row0 = blockIdx.x * 64 + w * 16;
    const floatx4 zero = {0.f, 0.f, 0.f, 0.f};

    floatx4 acc[2] = {zero, zero};

#pragma unroll
    for (int kt = 0; kt < 8; ++kt) {
        bf16x8 a0 = *(const bf16x8*)&attn16[(size_t)(row0 + lm) * 256 + kt * 32 + lq * 8];
        bf16x8 b0 = *(const bf16x8*)&wofrag[((kt * 2 + 0) * 64 + l) * 8];
        bf16x8 b1 = *(const bf16x8*)&wofrag[((kt * 2 + 1) * 64 + l) * 8];
        acc[0] = __builtin_amdgcn_mfma_f32_16x16x32_bf16(a0, b0, acc[0], 0, 0, 0);
        acc[1] = __builtin_amdgcn_mfma_f32_16x16x32_bf16(a0, b1, acc[1], 0, 0, 0);
    }

    float bov[2] = {bo[lm], bo[16 + lm]};
#pragma unroll
    for (int nt = 0; nt < 2; ++nt)
#pragma unroll
        for (int r = 0; r < 4; ++r)
            out[(size_t)(row0 + lq * 4 + r) * NC + nt * 16 + lm]
                = acc[nt][r] + bov[nt];
}

// ---------------------------------------------------------------------------
extern "C" void kernel_launch(void* const* d_in, const int* in_sizes, int n_in,
                              void* d_out, int out_size, void* d_ws, size_t ws_size,
                              hipStream_t stream) {
    const float* m     = (const float*)d_in[0];
    const float* z     = (const float*)d_in[1];
    const float* ln_s  = (const float*)d_in[2];
    const float* ln_b  = (const float*)d_in[3];
    const float* lnb_s = (const float*)d_in[4];
    const float* lnb_b = (const float*)d_in[5];
    const float* wq    = (const float*)d_in[6];
    const float* wk    = (const float*)d_in[7];
    const float* wv    = (const float*)d_in[8];
    const float* wb    = (const float*)d_in[9];
    const float* wg    = (const float*)d_in[10];
    const float* wo    = (const float*)d_in[11];
    const float* bo    = (const float*)d_in[12];
    float* out = (float*)d_out;

    // ws: bias32 2 MB | wprep 64 KB | wofrag 16 KB | attn16 16.78 MB
    float* bias32 = (float*)d_ws;
    unsigned short* wprep  = (unsigned short*)((char*)d_ws + (2u << 20));
    unsigned short* wofrag = (unsigned short*)((char*)d_ws + (2u << 20) + 65536);
    unsigned short* attn16 = (unsigned short*)((char*)d_ws + (2u << 20) + 65536 + 16384);

    biasprep_kernel<<<1044, 256, 0, stream>>>(z, lnb_s, lnb_b, wb, wq, wk, wv, wg,
                                              wo, bias32, wprep, wofrag);
    attn_kernel<<<NS * NH, 256, 0, stream>>>(m, ln_s, ln_b, wprep, bias32, attn16);
    proj_kernel<<<(NS * NI) / 64, 256, 0, stream>>>(attn16, wofrag, bo, out);
}

// Round 7
// 118.231 us; speedup vs baseline: 1.7129x; 1.1852x over previous
//
#include <hip/hip_runtime.h>

constexpr int NC = 32;    // channels C
constexpr int NH = 8;     // heads
constexpr int NS = 128;   // s
constexpr int NI = 256;   // i (q rows)
constexpr int NJ = 256;   // j (kv rows)
constexpr float LN_EPS = 1e-5f;
constexpr float QSCALE = 0.17677669529663687f;   // C^-0.5
constexpr float LOG2E  = 1.4426950408889634f;

typedef __bf16 bf16x8 __attribute__((ext_vector_type(8)));
typedef __bf16 bf16x2 __attribute__((ext_vector_type(2)));
typedef float floatx4 __attribute__((ext_vector_type(4)));

__device__ __forceinline__ float fexp2(float x) {
#if __has_builtin(__builtin_amdgcn_exp2f)
    return __builtin_amdgcn_exp2f(x);
#else
    return exp2f(x);
#endif
}
__device__ __forceinline__ float frcp(float x) {
#if __has_builtin(__builtin_amdgcn_rcpf)
    return __builtin_amdgcn_rcpf(x);
#else
    return 1.0f / x;
#endif
}
// HW bf16 pack (v_cvt_pk_bf16_f32 on gfx950), RNE
__device__ __forceinline__ unsigned pk2c(float a, float b) {
    union { bf16x2 v; unsigned u; } c;
    c.v = bf16x2{(__bf16)a, (__bf16)b};
    return c.u;
}

// XOR-swizzled LDS offsets (shorts). Rows of 32 shorts (4 x 16B chunks):
// phys_chunk = chunk ^ ((row>>1)&3)  -> <=2-way banks on all b128 reads.
__device__ __forceinline__ int qkOff(int row, int chunk) {
    return row * 32 + ((chunk ^ ((row >> 1) & 3)) << 3);
}
// V^T rows of 256 shorts (32 chunks): phys_chunk = chunk ^ (c&7).
__device__ __forceinline__ int vOff(int c, int chunk) {
    return c * 256 + ((chunk ^ (c & 7)) << 3);
}
// 16x32 slab (per wave, per it), same swizzle family as qkOff.
__device__ __forceinline__ int pOff(int base, int row, int chunk) {
    return base + row * 32 + ((chunk ^ ((row >> 1) & 3)) << 3);
}

// ---------------------------------------------------------------------------
// Kernel 1 (merged): blocks 0..255   : pair bias -> fp32 MFMA-C-fragment layout
//                    blocks 256..271 : wq/wk/wv/wg fragment prep (bf16)
//                    blocks 272..275 : wo B-fragment prep (bf16)
// (Reverted to the best-measured R0/R3 shape; R6's regrid was confounded.)
// bias32 layout: off(h,i,j) = h*65536 + jc*8192 + w*2048 + (jt*4+it)*256 + l*4 + r
//   log2e folded in (exp2 path).
// ---------------------------------------------------------------------------
__global__ __launch_bounds__(256) void biasprep_kernel(
    const float* __restrict__ z, const float* __restrict__ lnb_s,
    const float* __restrict__ lnb_b, const float* __restrict__ wb,
    const float* __restrict__ wq, const float* __restrict__ wk,
    const float* __restrict__ wv, const float* __restrict__ wg,
    const float* __restrict__ wo,
    float* __restrict__ bias32, unsigned short* __restrict__ wprep,
    unsigned short* __restrict__ wofrag)
{
    const int b = blockIdx.x;
    const int t = threadIdx.x;
    if (b < 256) {
        // ---- bias: block = one i, threads = j. Coalesced z stage via LDS. ----
        __shared__ float zL[256 * 33];               // pitch 33: conflict-free rows
        const float4* src = (const float4*)(z + (size_t)b * NJ * NC);
#pragma unroll
        for (int k = 0; k < 8; ++k) {
            int idx = t + 256 * k;                   // float4 index
            float4 v = src[idx];
            int f = idx * 4;
            int j = f >> 5, c = f & 31;
            zL[j * 33 + c]     = v.x; zL[j * 33 + c + 1] = v.y;
            zL[j * 33 + c + 2] = v.z; zL[j * 33 + c + 3] = v.w;
        }
        __syncthreads();

        float x[NC];
#pragma unroll
        for (int c = 0; c < NC; ++c) x[c] = zL[t * 33 + c];
        float mu = 0.f;
#pragma unroll
        for (int c = 0; c < NC; ++c) mu += x[c];
        mu *= (1.0f / NC);
        float var = 0.f;
#pragma unroll
        for (int c = 0; c < NC; ++c) { float d = x[c] - mu; var += d * d; }
        var *= (1.0f / NC);
        float rs = rsqrtf(var + LN_EPS);
        float acc[NH];
#pragma unroll
        for (int h = 0; h < NH; ++h) acc[h] = 0.f;
#pragma unroll
        for (int c = 0; c < NC; ++c) {
            float xn = (x[c] - mu) * rs * lnb_s[c] + lnb_b[c];
#pragma unroll
            for (int h = 0; h < NH; ++h) acc[h] += xn * wb[c * NH + h];
        }
        const int i = b;
        const int w_ = i >> 6, it = (i >> 4) & 3, lm = i & 15;
        const int jc = t >> 5, jt = (t >> 4) & 1, lq = (t >> 2) & 3, r = t & 3;
        const int base = jc * 8192 + w_ * 2048 + (jt * 4 + it) * 256
                       + (lq * 16 + lm) * 4 + r;
#pragma unroll
        for (int h = 0; h < NH; ++h)
            bias32[h * 65536 + base] = acc[h] * LOG2E;
    } else if (b < 272) {
        // ---- QKVG weight fragments ----
        int g = (b - 256) * 256 + t;                 // 0..4095
        int p  = g >> 10;
        int h  = (g >> 7) & 7;
        int ct = (g >> 6) & 1;
        int l  = g & 63;
        const float* W = (p == 0) ? wq : (p == 1) ? wk : (p == 2) ? wv : wg;
        float scale = (p == 0) ? QSCALE * LOG2E : (p == 3) ? LOG2E : 1.0f;
        int col = 32 * h + 16 * ct + (l & 15);
        int r0  = 8 * (l >> 4);
        float v[8];
#pragma unroll
        for (int e = 0; e < 8; ++e) v[e] = W[(r0 + e) * 256 + col] * scale;
        uint4 u;
        u.x = pk2c(v[0], v[1]); u.y = pk2c(v[2], v[3]);
        u.z = pk2c(v[4], v[5]); u.w = pk2c(v[6], v[7]);
        *(uint4*)&wprep[g * 8] = u;
    } else {
        // ---- wo B-fragments ----
        int g = (b - 272) * 256 + t;                 // 0..1023
        int tile = g >> 6;                           // kt*2+nt
        int l = g & 63;
        int kt = tile >> 1, nt = tile & 1;
        int r0 = kt * 32 + 8 * (l >> 4);
        int col = nt * 16 + (l & 15);
        float v[8];
#pragma unroll
        for (int e = 0; e < 8; ++e) v[e] = wo[(r0 + e) * 32 + col];
        uint4 u;
        u.x = pk2c(v[0], v[1]); u.y = pk2c(v[2], v[3]);
        u.z = pk2c(v[4], v[5]); u.w = pk2c(v[6], v[7]);
        *(uint4*)&wofrag[g * 8] = u;
    }
}

// ---------------------------------------------------------------------------
// Kernel 2: all-MFMA fused attention. 48 KB LDS -> 3 blocks/CU.
// R7 schedule change (single variable vs R6): the j-loop was stall-bound on
// per-step bias32 L2 loads feeding the QK MFMA C-operand (VGPR=68 proved the
// compiler never prefetched them). Now:
//   (1) all 8 bias C-loads hoisted to registers at jc-top (Cre[4][2]);
//   (2) full A/B phase split: A = QK+exp2+pack+slab-write for all 4 its,
//       B = 4 slab-reads then 8 PV MFMAs (write->read distance ~3 A-phases).
// Per-it slabs retained; denominator on VALU; no unroll pragma.
// LDS: KX (X -> Q^T -> K) 16K | Vt (V^T [c][j]) 16K | Pbuf 16K = 48 KB.
// ---------------------------------------------------------------------------
__global__ __launch_bounds__(256, 3) void attn_kernel(
    const float* __restrict__ m, const float* __restrict__ ln_s,
    const float* __restrict__ ln_b,
    const unsigned short* __restrict__ wprep,
    const float* __restrict__ bias32,
    unsigned short* __restrict__ attn16)
{
    __shared__ unsigned short KX[256 * 32];    // X -> Q^T -> K rows (qkOff)
    __shared__ unsigned short Vt[32 * 256];    // V^T [c][j] (vOff)
    __shared__ unsigned short Pbuf[4 * 2048];  // per-wave, per-it 16x32 slabs

    const int t = threadIdx.x;
    const int h = blockIdx.x & 7;
    const int s = blockIdx.x >> 3;
    const int l = t & 63, w = t >> 6;
    const int lm = l & 15, lq = l >> 4;
    const int ibase = w * 64;
    const int pwb = w * 2048;
    const floatx4 zero = {0.f, 0.f, 0.f, 0.f};

    // ---- Phase 1: LN(m[s][t]) -> KX row t (bf16, swizzled). Wave-private. ----
    {
        const float4* mr = (const float4*)(m + ((size_t)s * NI + t) * NC);
        float x[NC];
#pragma unroll
        for (int k = 0; k < 8; ++k) {
            float4 v = mr[k];
            x[4*k] = v.x; x[4*k+1] = v.y; x[4*k+2] = v.z; x[4*k+3] = v.w;
        }
        float mu = 0.f;
#pragma unroll
        for (int c = 0; c < NC; ++c) mu += x[c];
        mu *= (1.0f / NC);
        float var = 0.f;
#pragma unroll
        for (int c = 0; c < NC; ++c) { float d = x[c] - mu; var += d * d; }
        var *= (1.0f / NC);
        float rs = rsqrtf(var + LN_EPS);
#pragma unroll
        for (int k = 0; k < 4; ++k) {
            uint4 u;
            u.x = pk2c((x[8*k+0]-mu)*rs*ln_s[8*k+0]+ln_b[8*k+0],
                       (x[8*k+1]-mu)*rs*ln_s[8*k+1]+ln_b[8*k+1]);
            u.y = pk2c((x[8*k+2]-mu)*rs*ln_s[8*k+2]+ln_b[8*k+2],
                       (x[8*k+3]-mu)*rs*ln_s[8*k+3]+ln_b[8*k+3]);
            u.z = pk2c((x[8*k+4]-mu)*rs*ln_s[8*k+4]+ln_b[8*k+4],
                       (x[8*k+5]-mu)*rs*ln_s[8*k+5]+ln_b[8*k+5]);
            u.w = pk2c((x[8*k+6]-mu)*rs*ln_s[8*k+6]+ln_b[8*k+6],
                       (x[8*k+7]-mu)*rs*ln_s[8*k+7]+ln_b[8*k+7]);
            *(uint4*)&KX[qkOff(t, k)] = u;
        }
    }
    // no barrier: wave-private rows; DS pipe is in-order per wave

    // ---- Phase 2: MFMA projections. Gate deferred to epilogue. ----
    const unsigned short* wp = wprep + ((size_t)h * 128 + l) * 8;
    bf16x8 wfQ[2], wfK[2], wfV[2];
#pragma unroll
    for (int ct = 0; ct < 2; ++ct) {
        wfQ[ct] = *(const bf16x8*)&wp[(0 * 1024 + ct * 64) * 8];
        wfK[ct] = *(const bf16x8*)&wp[(1 * 1024 + ct * 64) * 8];
        wfV[ct] = *(const bf16x8*)&wp[(2 * 1024 + ct * 64) * 8];
    }
    bf16x8 Xb[4];                                 // retained for epilogue gate
#pragma unroll
    for (int it = 0; it < 4; ++it)
        Xb[it] = *(const bf16x8*)&KX[qkOff(ibase + it * 16 + lm, lq)];
    // KX (X) now dead for this wave -> reuse rows for Q^T

    // Q^T rows [i][c]  (D[c][i]: lane lm = i, regs = 4 consecutive c)
#pragma unroll
    for (int it = 0; it < 4; ++it)
#pragma unroll
        for (int ct = 0; ct < 2; ++ct) {
            floatx4 d = __builtin_amdgcn_mfma_f32_16x16x32_bf16(wfQ[ct], Xb[it], zero, 0, 0, 0);
            uint2 u; u.x = pk2c(d[0], d[1]); u.y = pk2c(d[2], d[3]);
            int row = ibase + it * 16 + lm;
            *(uint2*)&KX[qkOff(row, 2 * ct + (lq >> 1)) + (lq & 1) * 4] = u;
        }
    // Hoist own Q^T B-frags BEFORE K overwrites the same rows
    bf16x8 Qb[4];
#pragma unroll
    for (int it = 0; it < 4; ++it)
        Qb[it] = *(const bf16x8*)&KX[qkOff(ibase + it * 16 + lm, lq)];

    // K rows [j][c] -> KX (overwrite Q^T; own rows, in-order DS pipe)
#pragma unroll
    for (int it = 0; it < 4; ++it)
#pragma unroll
        for (int ct = 0; ct < 2; ++ct) {
            floatx4 d = __builtin_amdgcn_mfma_f32_16x16x32_bf16(wfK[ct], Xb[it], zero, 0, 0, 0);
            uint2 u; u.x = pk2c(d[0], d[1]); u.y = pk2c(d[2], d[3]);
            int row = ibase + it * 16 + lm;
            *(uint2*)&KX[qkOff(row, 2 * ct + (lq >> 1)) + (lq & 1) * 4] = u;
        }

    // V -> Vt [c][j]  (D[j][c']: lane lm = c', regs = 4 consecutive j)
#pragma unroll
    for (int jt = 0; jt < 4; ++jt)
#pragma unroll
        for (int ct = 0; ct < 2; ++ct) {
            floatx4 d = __builtin_amdgcn_mfma_f32_16x16x32_bf16(Xb[jt], wfV[ct], zero, 0, 0, 0);
            uint2 u; u.x = pk2c(d[0], d[1]); u.y = pk2c(d[2], d[3]);
            int c = ct * 16 + lm;
            int chunk = 8 * w + 2 * jt + (lq >> 1);
            *(uint2*)&Vt[vOff(c, chunk) + (lq & 1) * 4] = u;
        }

    __syncthreads();   // KX (K) / Vt visible to all waves (the only barrier)

    floatx4 accO[2][4];
#pragma unroll
    for (int ct = 0; ct < 2; ++ct)
#pragma unroll
        for (int it = 0; it < 4; ++it) accO[ct][it] = zero;
    float accLv[4] = {0.f, 0.f, 0.f, 0.f};        // denominator, VALU (lane = i)

    const float* bptr = bias32 + (size_t)h * 65536 + w * 2048 + l * 4;

    // ---- Phase 3: j-loop, 32 j/iter; C prefetch + A/B phase split ----
    for (int jc = 0; jc < 8; ++jc) {
        const float* bj = bptr + jc * 8192;

        // (1) hoisted bias C-loads: 8 x b128 issued back-to-back
        floatx4 Cre[4][2];
#pragma unroll
        for (int it = 0; it < 4; ++it) {
            Cre[it][0] = *(const floatx4*)(bj + it * 256);
            Cre[it][1] = *(const floatx4*)(bj + (4 + it) * 256);
        }
        bf16x8 Ka0 = *(const bf16x8*)&KX[qkOff(jc * 32 + lm, lq)];
        bf16x8 Ka1 = *(const bf16x8*)&KX[qkOff(jc * 32 + 16 + lm, lq)];
        bf16x8 Va0 = *(const bf16x8*)&Vt[vOff(lm, 4 * jc + lq)];
        bf16x8 Va1 = *(const bf16x8*)&Vt[vOff(16 + lm, 4 * jc + lq)];

        // (2a) Phase A: QK + exp2 + pack + slab-write, all 4 its
#pragma unroll
        for (int it = 0; it < 4; ++it) {
            const int pb = pwb + it * 512;         // private slab per (wave,it)
            floatx4 S0 = __builtin_amdgcn_mfma_f32_16x16x32_bf16(Ka0, Qb[it], Cre[it][0], 0, 0, 0);
            floatx4 S1 = __builtin_amdgcn_mfma_f32_16x16x32_bf16(Ka1, Qb[it], Cre[it][1], 0, 0, 0);
            float p0 = fexp2(S0[0]), p1 = fexp2(S0[1]);
            float p2 = fexp2(S0[2]), p3 = fexp2(S0[3]);
            float p4 = fexp2(S1[0]), p5 = fexp2(S1[1]);
            float p6 = fexp2(S1[2]), p7 = fexp2(S1[3]);
            accLv[it] += ((p0 + p1) + (p2 + p3)) + ((p4 + p5) + (p6 + p7));
            uint2 u0; u0.x = pk2c(p0, p1); u0.y = pk2c(p2, p3);
            uint2 u1; u1.x = pk2c(p4, p5); u1.y = pk2c(p6, p7);
            // j = 16*jt + 4*lq + r -> chunk = 2*jt + (lq>>1), off (lq&1)*4
            *(uint2*)&Pbuf[pOff(pb, lm, 0 + (lq >> 1)) + (lq & 1) * 4] = u0;
            *(uint2*)&Pbuf[pOff(pb, lm, 2 + (lq >> 1)) + (lq & 1) * 4] = u1;
        }

        // (2b) Phase B: batched slab-reads, then PV MFMAs
        bf16x8 Pb0 = *(const bf16x8*)&Pbuf[pOff(pwb + 0 * 512, lm, lq)];
        bf16x8 Pb1 = *(const bf16x8*)&Pbuf[pOff(pwb + 1 * 512, lm, lq)];
        bf16x8 Pb2 = *(const bf16x8*)&Pbuf[pOff(pwb + 2 * 512, lm, lq)];
        bf16x8 Pb3 = *(const bf16x8*)&Pbuf[pOff(pwb + 3 * 512, lm, lq)];
        accO[0][0] = __builtin_amdgcn_mfma_f32_16x16x32_bf16(Va0, Pb0, accO[0][0], 0, 0, 0);
        accO[1][0] = __builtin_amdgcn_mfma_f32_16x16x32_bf16(Va1, Pb0, accO[1][0], 0, 0, 0);
        accO[0][1] = __builtin_amdgcn_mfma_f32_16x16x32_bf16(Va0, Pb1, accO[0][1], 0, 0, 0);
        accO[1][1] = __builtin_amdgcn_mfma_f32_16x16x32_bf16(Va1, Pb1, accO[1][1], 0, 0, 0);
        accO[0][2] = __builtin_amdgcn_mfma_f32_16x16x32_bf16(Va0, Pb2, accO[0][2], 0, 0, 0);
        accO[1][2] = __builtin_amdgcn_mfma_f32_16x16x32_bf16(Va1, Pb2, accO[1][2], 0, 0, 0);
        accO[0][3] = __builtin_amdgcn_mfma_f32_16x16x32_bf16(Va0, Pb3, accO[0][3], 0, 0, 0);
        accO[1][3] = __builtin_amdgcn_mfma_f32_16x16x32_bf16(Va1, Pb3, accO[1][3], 0, 0, 0);
    }

    // ---- Epilogue: reduce L over lq, gate from retained Xb, store ----
    // accO / gate orientation: lane lm = i, regs = c' (4*lq + r per ct).
    {
        bf16x8 wfG0 = *(const bf16x8*)&wp[(3 * 1024 + 0 * 64) * 8];
        bf16x8 wfG1 = *(const bf16x8*)&wp[(3 * 1024 + 1 * 64) * 8];
#pragma unroll
        for (int it = 0; it < 4; ++it) {
            float L = accLv[it];
            L += __shfl_xor(L, 16, 64);
            L += __shfl_xor(L, 32, 64);
            const float inv = frcp(L);               // L[i = ibase + it*16 + lm]
            floatx4 d0 = __builtin_amdgcn_mfma_f32_16x16x32_bf16(wfG0, Xb[it], zero, 0, 0, 0);
            floatx4 d1 = __builtin_amdgcn_mfma_f32_16x16x32_bf16(wfG1, Xb[it], zero, 0, 0, 0);
            const size_t rowb = ((size_t)s * NI + ibase + it * 16 + lm) * 256 + h * 32;
            {
                float o0 = accO[0][it][0] * inv * frcp(1.0f + fexp2(-d0[0]));
                float o1 = accO[0][it][1] * inv * frcp(1.0f + fexp2(-d0[1]));
                float o2 = accO[0][it][2] * inv * frcp(1.0f + fexp2(-d0[2]));
                float o3 = accO[0][it][3] * inv * frcp(1.0f + fexp2(-d0[3]));
                uint2 u; u.x = pk2c(o0, o1); u.y = pk2c(o2, o3);
                *(uint2*)&attn16[rowb + 0 * 16 + lq * 4] = u;
            }
            {
                float o0 = accO[1][it][0] * inv * frcp(1.0f + fexp2(-d1[0]));
                float o1 = accO[1][it][1] * inv * frcp(1.0f + fexp2(-d1[1]));
                float o2 = accO[1][it][2] * inv * frcp(1.0f + fexp2(-d1[2]));
                float o3 = accO[1][it][3] * inv * frcp(1.0f + fexp2(-d1[3]));
                uint2 u; u.x = pk2c(o0, o1); u.y = pk2c(o2, o3);
                *(uint2*)&attn16[rowb + 1 * 16 + lq * 4] = u;
            }
        }
    }
}

// ---------------------------------------------------------------------------
// Kernel 3: MFMA output projection. out = attn16(32768x256) @ wo(256x32) + bo
// (Reverted to the R0/R3 128-row shape.)
// ---------------------------------------------------------------------------
__global__ __launch_bounds__(256) void proj_kernel(
    const unsigned short* __restrict__ attn16,
    const unsigned short* __restrict__ wofrag,
    const float* __restrict__ bo, float* __restrict__ out)
{
    const int t = threadIdx.x;
    const int l = t & 63, w = t >> 6;
    const int lm = l & 15, lq = l >> 4;
    const int row0 = blockIdx.x * 128 + w * 32;
    const floatx4 zero = {0.f, 0.f, 0.f, 0.f};

    floatx4 acc[2][2];
#pragma unroll
    for (int it = 0; it < 2; ++it)
#pragma unroll
        for (int nt = 0; nt < 2; ++nt) acc[it][nt] = zero;

#pragma unroll 2
    for (int kt = 0; kt < 8; ++kt) {
        bf16x8 a0 = *(const bf16x8*)&attn16[(size_t)(row0 + lm) * 256 + kt * 32 + lq * 8];
        bf16x8 a1 = *(const bf16x8*)&attn16[(size_t)(row0 + 16 + lm) * 256 + kt * 32 + lq * 8];
        bf16x8 b0 = *(const bf16x8*)&wofrag[((kt * 2 + 0) * 64 + l) * 8];
        bf16x8 b1 = *(const bf16x8*)&wofrag[((kt * 2 + 1) * 64 + l) * 8];
        acc[0][0] = __builtin_amdgcn_mfma_f32_16x16x32_bf16(a0, b0, acc[0][0], 0, 0, 0);
        acc[0][1] = __builtin_amdgcn_mfma_f32_16x16x32_bf16(a0, b1, acc[0][1], 0, 0, 0);
        acc[1][0] = __builtin_amdgcn_mfma_f32_16x16x32_bf16(a1, b0, acc[1][0], 0, 0, 0);
        acc[1][1] = __builtin_amdgcn_mfma_f32_16x16x32_bf16(a1, b1, acc[1][1], 0, 0, 0);
    }

    float bov[2] = {bo[lm], bo[16 + lm]};
#pragma unroll
    for (int it = 0; it < 2; ++it)
#pragma unroll
        for (int nt = 0; nt < 2; ++nt)
#pragma unroll
            for (int r = 0; r < 4; ++r)
                out[(size_t)(row0 + it * 16 + lq * 4 + r) * NC + nt * 16 + lm]
                    = acc[it][nt][r] + bov[nt];
}

// ---------------------------------------------------------------------------
extern "C" void kernel_launch(void* const* d_in, const int* in_sizes, int n_in,
                              void* d_out, int out_size, void* d_ws, size_t ws_size,
                              hipStream_t stream) {
    const float* m     = (const float*)d_in[0];
    const float* z     = (const float*)d_in[1];
    const float* ln_s  = (const float*)d_in[2];
    const float* ln_b  = (const float*)d_in[3];
    const float* lnb_s = (const float*)d_in[4];
    const float* lnb_b = (const float*)d_in[5];
    const float* wq    = (const float*)d_in[6];
    const float* wk    = (const float*)d_in[7];
    const float* wv    = (const float*)d_in[8];
    const float* wb    = (const float*)d_in[9];
    const float* wg    = (const float*)d_in[10];
    const float* wo    = (const float*)d_in[11];
    const float* bo    = (const float*)d_in[12];
    float* out = (float*)d_out;

    // ws: bias32 2 MB | wprep 64 KB | wofrag 16 KB | attn16 16.78 MB
    float* bias32 = (float*)d_ws;
    unsigned short* wprep  = (unsigned short*)((char*)d_ws + (2u << 20));
    unsigned short* wofrag = (unsigned short*)((char*)d_ws + (2u << 20) + 65536);
    unsigned short* attn16 = (unsigned short*)((char*)d_ws + (2u << 20) + 65536 + 16384);

    biasprep_kernel<<<276, 256, 0, stream>>>(z, lnb_s, lnb_b, wb, wq, wk, wv, wg,
                                             wo, bias32, wprep, wofrag);
    attn_kernel<<<NS * NH, 256, 0, stream>>>(m, ln_s, ln_b, wprep, bias32, attn16);
    proj_kernel<<<(NS * NI) / 128, 256, 0, stream>>>(attn16, wofrag, bo, out);
}